// Round 10
// baseline (1418.812 us; speedup 1.0000x reference)
//
#include <hip/hip_runtime.h>

#define T_STEPS 256
#define HID 40
#define EPB 8
#define NTHR 512
#define AST 136          // row stride (shorts) for ALL state buffers
#define BS2 (16 * AST)   // parity stride (shorts) = 2176

typedef __attribute__((ext_vector_type(8))) short bf16x8;
typedef __attribute__((ext_vector_type(4))) float f32x4;

__device__ __forceinline__ unsigned short bf16_rne(float v) {
    unsigned int x = __float_as_uint(v);
    unsigned int r = x + 0x7FFFu + ((x >> 16) & 1u);
    return (unsigned short)(r >> 16);
}
__device__ __forceinline__ float bf16f(unsigned short h) {
    return __uint_as_float(((unsigned int)h) << 16);
}
__device__ __forceinline__ float sigm(float v)  { return 1.0f / (1.0f + __expf(-v)); }
__device__ __forceinline__ float tanh_f(float v){ return 1.0f - 2.0f / (__expf(2.0f * v) + 1.0f); }

// Weights = A-operand (M=positions), state = B-operand (N=elems); lane (e,q) of
// tile T gets [r_pre, z_pre, nx, nh] of unit 4T+q in its 4 C-regs (r9-verified).
#define MF(A_, B_, C_) C_ = __builtin_amdgcn_mfma_f32_16x16x32_bf16(A_, B_, C_, 0, 0, 0)
#define PINV(v) asm volatile("" : "+v"(v))

// k'-space: [0,2K) interleaved (hi,lo) state pairs vs wh; [2K,3K) hi2 vs wl.
// 3-term split wh*hi + wh*lo + wl*hi (r7-r9 proven, absmax 2e-3). row<0 => 0.
__device__ bf16x8 wfrag(const float* W, int stride, int K, int row, int c, int qrow) {
    bf16x8 f;
    #pragma unroll
    for (int j = 0; j < 8; ++j) f[j] = 0;
    if (row < 0) return f;
    #pragma unroll
    for (int j = 0; j < 8; ++j) {
        const int kp = 32 * c + qrow * 8 + j;
        if (kp < 2 * K) {
            f[j] = (short)bf16_rne(W[row * stride + (kp >> 1)]);
        } else if (kp < 3 * K) {
            const float w = W[row * stride + (kp - 2 * K)];
            const unsigned short hb = bf16_rne(w);
            f[j] = (short)bf16_rne(w - bf16f(hb));
        }
    }
    return f;
}

// 2 blocks/CU (grid 512, EPB=8) + ping-pong buffers -> 1 barrier/step.
// 8 waves: 0-3 layer0, 4-7 layer1; tiles/wave {3,3,2,2} (10 tiles/layer).
// launch_bounds(512,4): VGPR<=128 so 2 blocks (16 waves) co-reside per CU.
__global__ __launch_bounds__(NTHR, 4)
void gru2_kernel(const float* __restrict__ x,
                 const float* __restrict__ Wih0, const float* __restrict__ Whh0,
                 const float* __restrict__ bih0, const float* __restrict__ bhh0,
                 const float* __restrict__ Wih1, const float* __restrict__ Whh1,
                 const float* __restrict__ bih1, const float* __restrict__ bhh1,
                 float* __restrict__ out)
{
    // [parity][row][k']; rows 0-7 = elems, rows 8-15 permanently zero (B pad)
    __shared__ __align__(16) unsigned short A0[2][16][AST];  // h0
    __shared__ __align__(16) unsigned short A1[2][16][AST];  // h1
    __shared__ __align__(16) unsigned short Ax[2][16][AST];  // x (data in 0..47)

    const int tid  = threadIdx.x;
    const int wid  = tid >> 6;
    const int l    = tid & 63;
    const int col  = l & 15;     // elem col (B n, C col)
    const int qrow = l >> 4;
    const int pm   = l & 15;     // A-frag position row
    const int ps   = pm & 3;     // slot (0=r,1=z,2=nx,3=nh)
    const int pu   = pm >> 2;    // unit-in-tile
    const int e0   = blockIdx.x * EPB;

    const bool isL1 = wid >= 4;
    const int  lw   = wid & 3;
    const int  NT   = (lw < 2) ? 3 : 2;
    const int  T0   = (lw < 2) ? lw * 3 : 6 + (lw - 2) * 2;

    const float* Whh = isL1 ? Whh1 : Whh0;
    const float* Wih = isL1 ? Wih1 : Wih0;
    const float* bih = isL1 ? bih1 : bih0;
    const float* bhh = isL1 ? bhh1 : bhh0;
    const int WST = isL1 ? 40 : 16;
    const int KX  = isL1 ? 40 : 16;

    bf16x8 Fh00,Fh01,Fh02,Fh03, Fh10,Fh11,Fh12,Fh13, Fh20,Fh21,Fh22,Fh23;
    bf16x8 Fx00,Fx01,Fx02,Fx03, Fx10,Fx11,Fx12,Fx13, Fx20,Fx21,Fx22,Fx23;
    float bb00,bb01,bb02,bb03, bb10,bb11,bb12,bb13, bb20,bb21,bb22,bb23;

#define BUILDT(J, TT, DEAD) { \
    const int uA = 4 * (TT) + pu; \
    const int rH = ((DEAD) || ps == 2) ? -1 : (ps == 0 ? uA : ps == 1 ? 40 + uA : 80 + uA); \
    const int rX = ((DEAD) || ps == 3) ? -1 : (ps == 0 ? uA : ps == 1 ? 40 + uA : 80 + uA); \
    Fh##J##0 = wfrag(Whh, 40, 40, rH, 0, qrow); \
    Fh##J##1 = wfrag(Whh, 40, 40, rH, 1, qrow); \
    Fh##J##2 = wfrag(Whh, 40, 40, rH, 2, qrow); \
    Fh##J##3 = wfrag(Whh, 40, 40, rH, 3, qrow); \
    Fx##J##0 = wfrag(Wih, WST, KX, rX, 0, qrow); \
    Fx##J##1 = wfrag(Wih, WST, KX, rX, 1, qrow); \
    Fx##J##2 = wfrag(Wih, WST, KX, rX, 2, qrow); \
    Fx##J##3 = wfrag(Wih, WST, KX, rX, 3, qrow); \
    const int uc = 4 * (TT) + qrow; \
    bb##J##0 = (DEAD) ? 0.f : bih[uc] + bhh[uc]; \
    bb##J##1 = (DEAD) ? 0.f : bih[40 + uc] + bhh[40 + uc]; \
    bb##J##2 = (DEAD) ? 0.f : bih[80 + uc]; \
    bb##J##3 = (DEAD) ? 0.f : bhh[80 + uc]; }

    BUILDT(0, T0,     0)
    BUILDT(1, T0 + 1, 0)
    BUILDT(2, (NT == 3) ? T0 + 2 : T0, (NT == 3) ? 0 : 1)

    PINV(Fh00); PINV(Fh01); PINV(Fh02); PINV(Fh03);
    PINV(Fh10); PINV(Fh11); PINV(Fh12); PINV(Fh13);
    PINV(Fh20); PINV(Fh21); PINV(Fh22); PINV(Fh23);
    PINV(Fx00); PINV(Fx01); PINV(Fx02); PINV(Fx03);
    PINV(Fx10); PINV(Fx11); PINV(Fx12); PINV(Fx13);
    PINV(Fx20); PINV(Fx21); PINV(Fx22); PINV(Fx23);
    asm volatile("" : "+v"(bb00), "+v"(bb01), "+v"(bb02), "+v"(bb03));
    asm volatile("" : "+v"(bb10), "+v"(bb11), "+v"(bb12), "+v"(bb13));
    asm volatile("" : "+v"(bb20), "+v"(bb21), "+v"(bb22), "+v"(bb23));

    const int U0 = 4 * T0 + qrow, U1 = U0 + 4;
    const int U2 = 4 * ((NT == 3) ? T0 + 2 : T0) + qrow;
    float h0_ = 0.f, h1_ = 0.f, h2_ = 0.f;

    // base pointers (parity offset added per step)
    const unsigned short* shB = (isL1 ? &A1[0][0][0] : &A0[0][0][0]) + col * AST + qrow * 8;
    const unsigned short* sxB = (isL1 ? &A0[0][0][0] : &Ax[0][0][0]) + col * AST + qrow * 8;
    unsigned short*       wpB = (isL1 ? &A1[0][0][0] : &A0[0][0][0]) + col * AST;

    // ---- init: zero all buffers/parities (pads + rows 8-15 MUST stay 0) ----
    for (int idx = tid; idx < 2 * 16 * AST; idx += NTHR) {
        (&A0[0][0][0])[idx] = 0; (&A1[0][0][0])[idx] = 0; (&Ax[0][0][0])[idx] = 0;
    }
    __syncthreads();
    const bool xth = tid < 128;
    const int xe = tid >> 4, xk = tid & 15;
    const float* xrow = x + (size_t)(e0 + xe) * (T_STEPS * 16) + xk;
    float xold = 0.f;
    if (xth) {
        const float v = xrow[0];
        const unsigned short hb = bf16_rne(v);
        const unsigned short lb = bf16_rne(v - bf16f(hb));
        *(unsigned int*)(&Ax[0][xe][2 * xk]) = (unsigned int)hb | ((unsigned int)lb << 16);
        Ax[0][xe][32 + xk] = hb;
        xold = xrow[16];
    }
    __syncthreads();

    bf16x8 Zf;
    #pragma unroll
    for (int j = 0; j < 8; ++j) Zf[j] = 0;

#define TILE(J, U, H, DEADJ) { \
    f32x4 c = (f32x4){bb##J##0, bb##J##1, bb##J##2, bb##J##3}; \
    MF(Fh##J##0, SH0, c); MF(Fh##J##1, SH1, c); MF(Fh##J##2, SH2, c); MF(Fh##J##3, SH3, c); \
    MF(Fx##J##0, SX0, c); MF(Fx##J##1, SX1, c); \
    if (isL1) { MF(Fx##J##2, SX2, c); MF(Fx##J##3, SX3, c); } \
    if (active && !(DEADJ)) { \
        const float r_ = sigm(c[0]); \
        const float z_ = sigm(c[1]); \
        const float n_ = tanh_f(c[2] + r_ * c[3]); \
        H = (1.0f - z_) * n_ + z_ * H; \
        if (col < EPB) { \
            const unsigned short hb_ = bf16_rne(H); \
            const unsigned short lb_ = bf16_rne(H - bf16f(hb_)); \
            *(unsigned int*)(wpa + 2 * (U)) = (unsigned int)hb_ | ((unsigned int)lb_ << 16); \
            wpa[80 + (U)] = hb_; } } }

    for (int t = 0; t <= T_STEPS; ++t) {
        const int ro = (t & 1) * BS2;   // read parity offset (shorts)
        const int wo = BS2 - ro;        // write parity offset

        float xnew = 0.f;
        if (xth && t + 2 < T_STEPS) xnew = xrow[(t + 2) * 16];

        const bf16x8 SH0 = *(const bf16x8*)(shB + ro);
        const bf16x8 SH1 = *(const bf16x8*)(shB + ro + 32);
        const bf16x8 SH2 = *(const bf16x8*)(shB + ro + 64);
        const bf16x8 SH3 = *(const bf16x8*)(shB + ro + 96);
        const bf16x8 SX0 = *(const bf16x8*)(sxB + ro);
        const bf16x8 SX1 = *(const bf16x8*)(sxB + ro + 32);
        bf16x8 SX2 = Zf, SX3 = Zf;
        if (isL1) { SX2 = *(const bf16x8*)(sxB + ro + 64); SX3 = *(const bf16x8*)(sxB + ro + 96); }

        const bool active = isL1 ? (t > 0) : (t < T_STEPS);
        unsigned short* wpa = wpB + wo;

        TILE(0, U0, h0_, 0)
        TILE(1, U1, h1_, 0)
        TILE(2, U2, h2_, NT == 2)

        // stage x[t+1] into the write-parity buffer
        if (xth && t < T_STEPS - 1) {
            const unsigned short hb = bf16_rne(xold);
            const unsigned short lb = bf16_rne(xold - bf16f(hb));
            *(unsigned int*)(&Ax[0][0][0] + xe * AST + wo + 2 * xk) =
                (unsigned int)hb | ((unsigned int)lb << 16);
            (&Ax[0][0][0])[xe * AST + wo + 32 + xk] = hb;
        }
        xold = xnew;
        __syncthreads();   // single barrier: write-parity becomes next read-parity
    }

    // ---- h1[255] from registers ----
    if (isL1 && col < EPB) {
        out[(size_t)(e0 + col) * HID + U0] = h0_;
        out[(size_t)(e0 + col) * HID + U1] = h1_;
        if (NT == 3) out[(size_t)(e0 + col) * HID + U2] = h2_;
    }
}

extern "C" void kernel_launch(void* const* d_in, const int* in_sizes, int n_in,
                              void* d_out, int out_size, void* d_ws, size_t ws_size,
                              hipStream_t stream) {
    const float* x    = (const float*)d_in[0];
    const float* Wih0 = (const float*)d_in[1];
    const float* Whh0 = (const float*)d_in[2];
    const float* bih0 = (const float*)d_in[3];
    const float* bhh0 = (const float*)d_in[4];
    const float* Wih1 = (const float*)d_in[5];
    const float* Whh1 = (const float*)d_in[6];
    const float* bih1 = (const float*)d_in[7];
    const float* bhh1 = (const float*)d_in[8];
    float* out = (float*)d_out;

    dim3 grid(4096 / EPB), block(NTHR);
    hipLaunchKernelGGL(gru2_kernel, grid, block, 0, stream,
                       x, Wih0, Whh0, bih0, bhh0, Wih1, Whh1, bih1, bhh1, out);
}

// Round 11
// 332.534 us; speedup vs baseline: 4.2667x; 4.2667x over previous
//
#include <hip/hip_runtime.h>

#define T_STEPS 256
#define HID 40
#define EPB 16
#define NTHR 1024
#define AST 136          // state row stride (shorts); 272 B keeps b128 reads 16B-aligned
#define BS2 (16 * AST)   // parity stride (shorts)
#define BUF (2 * BS2)    // per-buffer stride (shorts)

typedef __attribute__((ext_vector_type(8))) short bf16x8;
typedef __attribute__((ext_vector_type(4))) float f32x4;

__device__ __forceinline__ unsigned short bf16_rne(float v) {
    unsigned int x = __float_as_uint(v);
    unsigned int r = x + 0x7FFFu + ((x >> 16) & 1u);
    return (unsigned short)(r >> 16);
}
__device__ __forceinline__ float bf16f(unsigned short h) {
    return __uint_as_float(((unsigned int)h) << 16);
}
__device__ __forceinline__ float sigm(float v)  { return 1.0f / (1.0f + __expf(-v)); }
__device__ __forceinline__ float tanh_f(float v){ return 1.0f - 2.0f / (__expf(2.0f * v) + 1.0f); }

// Weights = A-operand (M=positions), state = B-operand (N=elems); lane (e,q) of
// tile T gets [r_pre, z_pre, nx, nh] of unit 4T+q in its 4 C-regs (r9/r10-verified).
#define MF(A_, B_, C_) C_ = __builtin_amdgcn_mfma_f32_16x16x32_bf16(A_, B_, C_, 0, 0, 0)
#define PINV(v) asm volatile("" : "+v"(v))

// k'-space: [0,2K) interleaved (hi,lo) state pairs vs wh; [2K,3K) hi2 vs wl.
// 3-term split wh*hi + wh*lo + wl*hi (r7-r10 proven, absmax 2e-3). row<0 => 0.
// For K=16 (L0 input), chunks 2,3 come out all-zero naturally.
__device__ bf16x8 wfrag(const float* W, int stride, int K, int row, int c, int qrow) {
    bf16x8 f;
    #pragma unroll
    for (int j = 0; j < 8; ++j) f[j] = 0;
    if (row < 0) return f;
    #pragma unroll
    for (int j = 0; j < 8; ++j) {
        const int kp = 32 * c + qrow * 8 + j;
        if (kp < 2 * K) {
            f[j] = (short)bf16_rne(W[row * stride + (kp >> 1)]);
        } else if (kp < 3 * K) {
            const float w = W[row * stride + (kp - 2 * K)];
            const unsigned short hb = bf16_rne(w);
            f[j] = (short)bf16_rne(w - bf16f(hb));
        }
    }
    return f;
}

// r10 lesson: launch_bounds cap 128 + 24 pinned frags/wave => SPILL (4 GB scratch
// traffic, 1.4 ms). This kernel: 16 waves/block, <=2 tiles/wave -> 14 frag names
// (56 VGPR) + 8 biases + staging ~32 => ~120 total, genuinely fits 128.
// One 1024-thr block/CU (grid 256, EPB=16), ping-pong buffers, 1 barrier/step.
// Waves 0-5: layer0 (tiles 2,2,2,2,1,1); waves 6-15: layer1 (1 tile each).
__global__ __launch_bounds__(NTHR, 4)
void gru2_kernel(const float* __restrict__ x,
                 const float* __restrict__ Wih0, const float* __restrict__ Whh0,
                 const float* __restrict__ bih0, const float* __restrict__ bhh0,
                 const float* __restrict__ Wih1, const float* __restrict__ Whh1,
                 const float* __restrict__ bih1, const float* __restrict__ bhh1,
                 float* __restrict__ out)
{
    // S[buf][parity][elem][k']: buf 0 = h0, 1 = h1, 2 = x
    __shared__ __align__(16) unsigned short S[3][2][EPB][AST];

    const int tid  = threadIdx.x;
    const int wid  = tid >> 6;     // 0..15
    const int l    = tid & 63;
    const int col  = l & 15;       // elem (B n, C col)
    const int qrow = l >> 4;
    const int pm   = l & 15;       // A-frag position row
    const int ps   = pm & 3;       // slot (0=r,1=z,2=nx,3=nh)
    const int pu   = pm >> 2;      // unit-in-tile
    const int e0   = blockIdx.x * EPB;

    const bool isL1 = wid >= 6;
    const int  NT   = (!isL1 && wid < 4) ? 2 : 1;
    const int  T0   = isL1 ? (wid - 6) : (wid < 4 ? wid * 2 : wid + 4);
    const int  T1   = (NT == 2) ? T0 + 1 : T0;
    const bool dead1 = (NT != 2);

    const float* Whh = isL1 ? Whh1 : Whh0;
    const float* Wih = isL1 ? Wih1 : Wih0;
    const float* bih = isL1 ? bih1 : bih0;
    const float* bhh = isL1 ? bhh1 : bhh0;
    const int WST = isL1 ? 40 : 16;
    const int KX  = isL1 ? 40 : 16;

    // A-row indices for this lane's slots
    const int uA0 = 4 * T0 + pu;
    const int rH0 = (ps == 2) ? -1 : (ps == 0 ? uA0 : ps == 1 ? 40 + uA0 : 80 + uA0);
    const int rX0 = (ps == 3) ? -1 : (ps == 0 ? uA0 : ps == 1 ? 40 + uA0 : 80 + uA0);
    const int uA1 = 4 * T1 + pu;
    const int rH1 = (dead1 || ps == 2) ? -1 : (ps == 0 ? uA1 : ps == 1 ? 40 + uA1 : 80 + uA1);
    const int rX1 = (dead1 || ps == 3) ? -1 : (ps == 0 ? uA1 : ps == 1 ? 40 + uA1 : 80 + uA1);

    // ---- weight A-frags (14 names, union across roles) + biases, pinned ----
    bf16x8 Fh00 = wfrag(Whh, 40, 40, rH0, 0, qrow);
    bf16x8 Fh01 = wfrag(Whh, 40, 40, rH0, 1, qrow);
    bf16x8 Fh02 = wfrag(Whh, 40, 40, rH0, 2, qrow);
    bf16x8 Fh03 = wfrag(Whh, 40, 40, rH0, 3, qrow);
    bf16x8 Fx00 = wfrag(Wih, WST, KX, rX0, 0, qrow);
    bf16x8 Fx01 = wfrag(Wih, WST, KX, rX0, 1, qrow);
    bf16x8 Fx02 = wfrag(Wih, WST, KX, rX0, 2, qrow);  // zero for L0 (K=16)
    bf16x8 Fx03 = wfrag(Wih, WST, KX, rX0, 3, qrow);  // zero for L0
    bf16x8 Fh10 = wfrag(Whh, 40, 40, rH1, 0, qrow);
    bf16x8 Fh11 = wfrag(Whh, 40, 40, rH1, 1, qrow);
    bf16x8 Fh12 = wfrag(Whh, 40, 40, rH1, 2, qrow);
    bf16x8 Fh13 = wfrag(Whh, 40, 40, rH1, 3, qrow);
    bf16x8 Fx10 = wfrag(Wih, WST, KX, rX1, 0, qrow);
    bf16x8 Fx11 = wfrag(Wih, WST, KX, rX1, 1, qrow);

    const int uc0 = 4 * T0 + qrow;
    float bb0 = bih[uc0] + bhh[uc0];
    float bb1 = bih[40 + uc0] + bhh[40 + uc0];
    float bb2 = bih[80 + uc0];
    float bb3 = bhh[80 + uc0];
    const int uc1 = 4 * T1 + qrow;
    float bb4 = dead1 ? 0.f : (bih[uc1] + bhh[uc1]);
    float bb5 = dead1 ? 0.f : (bih[40 + uc1] + bhh[40 + uc1]);
    float bb6 = dead1 ? 0.f : bih[80 + uc1];
    float bb7 = dead1 ? 0.f : bhh[80 + uc1];

    PINV(Fh00); PINV(Fh01); PINV(Fh02); PINV(Fh03);
    PINV(Fx00); PINV(Fx01); PINV(Fx02); PINV(Fx03);
    PINV(Fh10); PINV(Fh11); PINV(Fh12); PINV(Fh13);
    PINV(Fx10); PINV(Fx11);
    asm volatile("" : "+v"(bb0), "+v"(bb1), "+v"(bb2), "+v"(bb3));
    asm volatile("" : "+v"(bb4), "+v"(bb5), "+v"(bb6), "+v"(bb7));

    // LDS offsets (shorts)
    const int rd_h = (isL1 ? BUF : 0) + col * AST + qrow * 8;        // self-layer h
    const int rd_x = (isL1 ? 0 : 2 * BUF) + col * AST + qrow * 8;    // input: h0 or x
    const int wr_b = (isL1 ? BUF : 0) + col * AST;
    unsigned short* Sb = &S[0][0][0][0];
    float h0_ = 0.f, h1_ = 0.f;

#define GATE_WB(U, H) { \
    const float r_ = sigm(c[0]); \
    const float z_ = sigm(c[1]); \
    const float n_ = tanh_f(c[2] + r_ * c[3]); \
    H = (1.0f - z_) * n_ + z_ * H; \
    const unsigned short hb_ = bf16_rne(H); \
    const unsigned short lb_ = bf16_rne(H - bf16f(hb_)); \
    *(unsigned int*)(Sb + wr_b + wo + 2 * (U)) = (unsigned int)hb_ | ((unsigned int)lb_ << 16); \
    (Sb + wr_b + wo)[80 + (U)] = hb_; }

    // ---- init: zero ALL of S (pads must stay 0), stage x[0], preload x[1] ----
    for (int idx = tid; idx < 3 * BUF; idx += NTHR) Sb[idx] = 0;
    __syncthreads();
    const bool xth = tid < 256;
    const int xe = tid >> 4, xk = tid & 15;
    const float* xrow = x + (size_t)(e0 + xe) * (T_STEPS * 16) + xk;
    float xold = 0.f;
    if (xth) {
        const float v = xrow[0];
        const unsigned short hb = bf16_rne(v);
        const unsigned short lb = bf16_rne(v - bf16f(hb));
        *(unsigned int*)(Sb + 2 * BUF + xe * AST + 2 * xk) = (unsigned int)hb | ((unsigned int)lb << 16);
        (Sb + 2 * BUF + xe * AST)[32 + xk] = hb;
        xold = xrow[16];
    }
    __syncthreads();

    for (int t = 0; t <= T_STEPS; ++t) {
        const int ro = (t & 1) * BS2;   // read parity
        const int wo = BS2 - ro;        // write parity

        float xnew = 0.f;
        if (xth && t + 2 < T_STEPS) xnew = xrow[(t + 2) * 16];

        const bf16x8 SH0 = *(const bf16x8*)(Sb + rd_h + ro);
        const bf16x8 SH1 = *(const bf16x8*)(Sb + rd_h + ro + 32);
        const bf16x8 SH2 = *(const bf16x8*)(Sb + rd_h + ro + 64);
        const bf16x8 SH3 = *(const bf16x8*)(Sb + rd_h + ro + 96);

        if (!isL1) {
            const bf16x8 SX0 = *(const bf16x8*)(Sb + rd_x + ro);
            const bf16x8 SX1 = *(const bf16x8*)(Sb + rd_x + ro + 32);
            const bool active = (t < T_STEPS);
            f32x4 c = (f32x4){bb0, bb1, bb2, bb3};
            MF(Fh00, SH0, c); MF(Fh01, SH1, c); MF(Fh02, SH2, c); MF(Fh03, SH3, c);
            MF(Fx00, SX0, c); MF(Fx01, SX1, c);
            if (active) GATE_WB(uc0, h0_);
            if (NT == 2) {
                c = (f32x4){bb4, bb5, bb6, bb7};
                MF(Fh10, SH0, c); MF(Fh11, SH1, c); MF(Fh12, SH2, c); MF(Fh13, SH3, c);
                MF(Fx10, SX0, c); MF(Fx11, SX1, c);
                if (active) GATE_WB(uc1, h1_);
            }
        } else {
            const bf16x8 SX0 = *(const bf16x8*)(Sb + rd_x + ro);
            const bf16x8 SX1 = *(const bf16x8*)(Sb + rd_x + ro + 32);
            const bf16x8 SX2 = *(const bf16x8*)(Sb + rd_x + ro + 64);
            const bf16x8 SX3 = *(const bf16x8*)(Sb + rd_x + ro + 96);
            f32x4 c = (f32x4){bb0, bb1, bb2, bb3};
            MF(Fh00, SH0, c); MF(Fh01, SH1, c); MF(Fh02, SH2, c); MF(Fh03, SH3, c);
            MF(Fx00, SX0, c); MF(Fx01, SX1, c); MF(Fx02, SX2, c); MF(Fx03, SX3, c);
            if (t > 0) GATE_WB(uc0, h0_);
        }

        // stage x[t+1] into the write parity
        if (xth && t < T_STEPS - 1) {
            const unsigned short hb = bf16_rne(xold);
            const unsigned short lb = bf16_rne(xold - bf16f(hb));
            *(unsigned int*)(Sb + 2 * BUF + xe * AST + wo + 2 * xk) =
                (unsigned int)hb | ((unsigned int)lb << 16);
            (Sb + 2 * BUF + xe * AST + wo)[32 + xk] = hb;
        }
        xold = xnew;
        __syncthreads();   // single barrier: write parity becomes next read parity
    }

    // ---- h1[255] straight from registers (L1 waves cover 10 tiles x 4 units) ----
    if (isL1) {
        out[(size_t)(e0 + col) * HID + uc0] = h0_;
    }
}

extern "C" void kernel_launch(void* const* d_in, const int* in_sizes, int n_in,
                              void* d_out, int out_size, void* d_ws, size_t ws_size,
                              hipStream_t stream) {
    const float* x    = (const float*)d_in[0];
    const float* Wih0 = (const float*)d_in[1];
    const float* Whh0 = (const float*)d_in[2];
    const float* bih0 = (const float*)d_in[3];
    const float* bhh0 = (const float*)d_in[4];
    const float* Wih1 = (const float*)d_in[5];
    const float* Whh1 = (const float*)d_in[6];
    const float* bih1 = (const float*)d_in[7];
    const float* bhh1 = (const float*)d_in[8];
    float* out = (float*)d_out;

    dim3 grid(4096 / EPB), block(NTHR);
    hipLaunchKernelGGL(gru2_kernel, grid, block, 0, stream,
                       x, Wih0, Whh0, bih0, bhh0, Wih1, Whh1, bih1, bhh1, out);
}